// Round 15
// baseline (136.669 us; speedup 1.0000x reference)
//
#include <hip/hip_runtime.h>
#include <stdint.h>

#define NB 16
#define HH 512
#define WW 512
#define HW (HH*WW)          // 262144
#define NBINS 4096

typedef unsigned long long u64;

__device__ __forceinline__ float clip01(float v){ return fminf(fmaxf(v, 0.0f), 1.0f); }
__device__ __forceinline__ int refl(int i, int n){ if (i < 0) i = -i; if (i >= n) i = 2*n - 2 - i; return i; }
__device__ __forceinline__ int clampi(int i, int lo, int hi){ return i < lo ? lo : (i > hi ? hi : i); }

// ---------------- gray + comb (vectorized), also zeroes hist + completion counters ----------------
__global__ void __launch_bounds__(256) k_gray(const float* __restrict__ x,
                                              const float* __restrict__ mean,
                                              const float* __restrict__ stdv,
                                              float* __restrict__ gray,
                                              uint16_t* __restrict__ comb,
                                              uint4* __restrict__ hist4,
                                              uint32_t* __restrict__ cnt)
{
#pragma clang fp contract(off)
  int b = blockIdx.x, tid = threadIdx.x;
  if (b < 64) hist4[b*256 + tid] = make_uint4(0u,0u,0u,0u);   // 256 KB hist zero
  if (b == 64 && tid < NB) cnt[tid] = 0u;                     // per-image b11 completion counters
  int img  = b >> 6;
  int base = (b & 63) * 4096;
  float m0 = mean[0], m1 = mean[1], m2 = mean[2];
  float s0 = stdv[0], s1 = stdv[1], s2 = stdv[2];
  const float* xb = x + (size_t)img * 3 * HW;
  float*     gb   = gray + (size_t)img*HW;
  uint16_t*  cb   = comb + (size_t)img*HW;
  #pragma unroll
  for (int it = 0; it < 4; it++){
    int f4 = it*256 + tid;
    int p  = base + f4*4;
    float4 r = *(const float4*)(xb + p);
    float4 g = *(const float4*)(xb + HW + p);
    float4 bl= *(const float4*)(xb + 2*HW + p);
    float xr[4] = {r.x, r.y, r.z, r.w};
    float xg[4] = {g.x, g.y, g.z, g.w};
    float xbl[4] = {bl.x, bl.y, bl.z, bl.w};
    float gy[4]; uint16_t cc[4];
    #pragma unroll
    for (int j = 0; j < 4; j++){
      float cr = clip01(xr[j]*s0 + m0);
      float cg = clip01(xg[j]*s1 + m1);
      float cbv= clip01(xbl[j]*s2 + m2);
      gy[j] = 0.299f*cr + 0.587f*cg + 0.114f*cbv;
      int c = ((int)rintf(cr*15.0f))*256 + ((int)rintf(cg*15.0f))*16 + (int)rintf(cbv*15.0f);
      cc[j] = (uint16_t)c;
    }
    *(float4*)(gb + p) = make_float4(gy[0], gy[1], gy[2], gy[3]);
    ushort4 cv; cv.x = cc[0]; cv.y = cc[1]; cv.z = cc[2]; cv.w = cc[3];
    *(ushort4*)(cb + p) = cv;
  }
}

// ---------------- fused blur5 + sobel + NMS + threshold -> bitmasks ----------------
// 32x64 tile; sdir aliased into ubuf tail (mag uses 2278 of 2920 floats) -> 7 blocks/CU.
__global__ void __launch_bounds__(256) k_canny(const float* __restrict__ gray,
                                               u64* __restrict__ A, u64* __restrict__ Sb)
{
#pragma clang fp contract(off)
  __shared__ float ubuf[40*73];      // gray (40x72, s73); then mag (34x66, s67) in [0,2278) + sdir
  __shared__ float blr[36*69];       // blurred (36x68, s69)
  uint8_t* sdir = (uint8_t*)&ubuf[2278];
  int b = blockIdx.x;
  int img = b >> 7;
  int t = b & 127;
  int y0 = (t >> 3) << 5;
  int x0 = (t & 7) << 6;
  const float* gb = gray + (size_t)img*HW;
  int tid = threadIdx.x;
  float g5[5]; { float s=0.0f; for(int i=0;i<5;i++){ float tt=(float)i-2.0f; g5[i]=expf(-(tt*tt)/2.0f); s+=g5[i]; } for(int i=0;i<5;i++) g5[i]/=s; }
  // S1: load gray tile with reflect halo 4 (40 rows x 72 cols)
  for (int i = tid; i < 40*72; i += 256){
    int ly = i/72, lx = i - ly*72;
    int gy = refl(y0 - 4 + ly, HH);
    int gx = refl(x0 - 4 + lx, WW);
    ubuf[ly*73 + lx] = gb[gy*WW + gx];
  }
  __syncthreads();
  // S2: 5x5 blur, register-window column sweep (68 cols x 4 chunks of 9 rows)
  for (int task = tid; task < 272; task += 256){
    int lx = task % 68;
    int ly = (task / 68) * 9;
    float w[5][5];
    #pragma unroll
    for (int j = 0; j < 4; j++)
      #pragma unroll
      for (int k = 0; k < 5; k++)
        w[j][k] = ubuf[(ly+j)*73 + lx + k];
    #pragma unroll
    for (int s = 0; s < 9; s++){
      #pragma unroll
      for (int k = 0; k < 5; k++) w[4][k] = ubuf[(ly+s+4)*73 + lx + k];
      float acc = 0.0f;
      #pragma unroll
      for (int ky = 0; ky < 5; ky++)
        #pragma unroll
        for (int kx = 0; kx < 5; kx++)
          acc += (g5[ky]*g5[kx]) * w[ky][kx];
      blr[(ly+s)*69 + lx] = acc;
      #pragma unroll
      for (int j = 0; j < 4; j++)
        #pragma unroll
        for (int k = 0; k < 5; k++) w[j][k] = w[j+1][k];
    }
  }
  __syncthreads();
  // S3: sobel (clamp pad) -> mag (34x66) + dir (32x64); ubuf becomes mag
  for (int i = tid; i < 34*66; i += 256){
    int ly = i/66, lx = i - ly*66;
    int Y = y0 - 1 + ly, X = x0 - 1 + lx;
    float m = 0.0f;
    if (Y >= 0 && Y < HH && X >= 0 && X < WW){
      float v[3][3];
      for (int dy = 0; dy < 3; dy++){
        int Yl = clampi(Y + dy - 1, 0, HH-1) - (y0 - 2);
        for (int dx = 0; dx < 3; dx++){
          int Xl = clampi(X + dx - 1, 0, WW-1) - (x0 - 2);
          v[dy][dx] = blr[Yl*69 + Xl];
        }
      }
      float gx = (v[0][2] - v[0][0]) + 2.0f*(v[1][2] - v[1][0]) + (v[2][2] - v[2][0]);
      float gy = (v[2][0] + 2.0f*v[2][1] + v[2][2]) - (v[0][0] + 2.0f*v[0][1] + v[0][2]);
      m = sqrtf(gx*gx + gy*gy + 1e-6f);
      if (ly >= 1 && ly <= 32 && lx >= 1 && lx <= 64){
        float ax = fabsf(gx), ay = fabsf(gy);
        int d;
        if (ay <= 0.41421356237309503f*ax) d = (gx >= 0.0f) ? 0 : 4;
        else if (ay >= 2.4142135623730951f*ax) d = (gy > 0.0f) ? 2 : 6;
        else if (gx > 0.0f) d = (gy > 0.0f) ? 1 : 7;
        else d = (gy > 0.0f) ? 3 : 5;
        sdir[(ly-1)*64 + (lx-1)] = (uint8_t)d;
      }
    }
    ubuf[ly*67 + lx] = m;
  }
  __syncthreads();
  // S4: NMS + double threshold + ballot
  const int OY[8] = {0,1,1,1,0,-1,-1,-1};
  const int OX[8] = {1,1,0,-1,-1,-1,0,1};
  int lane = tid & 63, wv = tid >> 6;
  for (int j = 0; j < 8; j++){
    int y = j*4 + wv;
    int xx0 = lane;
    float m = ubuf[(y+1)*67 + (xx0+1)];
    int d  = sdir[y*64 + xx0];
    int d2 = (d + 4) & 7;
    float mp = 0.0f, mn = 0.0f;
    { int yy=y+OY[d],  xx=xx0+OX[d];  int gy=y0+yy, gx=x0+xx; if(gy>=0&&gy<HH&&gx>=0&&gx<WW) mp = ubuf[(yy+1)*67 + (xx+1)]; }
    { int yy=y+OY[d2], xx=xx0+OX[d2]; int gy=y0+yy, gx=x0+xx; if(gy>=0&&gy<HH&&gx>=0&&gx<WW) mn = ubuf[(yy+1)*67 + (xx+1)]; }
    bool keep = ((m - mp) > 0.0f) && ((m - mn) > 0.0f);
    float mf = keep ? m : 0.0f;
    bool strong = mf > 0.2f;
    bool weak   = (mf > 0.1f) && !strong;
    u64 wb = __ballot(weak);
    u64 sb = __ballot(strong);
    if (lane == 0){
      int gy = y0 + y;
      A [img*4096 + gy*8 + (x0>>6)] = wb;
      Sb[img*4096 + gy*8 + (x0>>6)] = sb;
    }
  }
}

// ---------------- hysteresis helpers ----------------
__device__ __forceinline__ u64 ks_flood(u64 g, u64 P){
  u64 p1 = P, g1 = g;
  g1 |= p1 & (g1 << 1);  p1 &= (p1 << 1);
  g1 |= p1 & (g1 << 2);  p1 &= (p1 << 2);
  g1 |= p1 & (g1 << 4);  p1 &= (p1 << 4);
  g1 |= p1 & (g1 << 8);  p1 &= (p1 << 8);
  g1 |= p1 & (g1 << 16); p1 &= (p1 << 16);
  g1 |= p1 & (g1 << 32);
  u64 p2 = P, g2 = g;
  g2 |= p2 & (g2 >> 1);  p2 &= (p2 >> 1);
  g2 |= p2 & (g2 >> 2);  p2 &= (p2 >> 2);
  g2 |= p2 & (g2 >> 4);  p2 &= (p2 >> 4);
  g2 |= p2 & (g2 >> 8);  p2 &= (p2 >> 8);
  g2 |= p2 & (g2 >> 16); p2 &= (p2 >> 16);
  g2 |= p2 & (g2 >> 32);
  return g1 | g2;
}

#define HROW(m, l, r_) ((m) | ((m)<<1) | ((m)>>1) | ((l)>>63) | ((r_)<<63))

#define UPD2(i) do{ \
    if (Pr[i] & ~Sr[i]){ \
      u64 Sv = Sr[i]; \
      u64 mu = ((i) > 0) ? Sr[(i)-1] : MU; \
      u64 md = ((i) < 7) ? Sr[(i)+1] : MD; \
      u64 lu = ((i) > 0) ? L[(i)-1]  : LUv; \
      u64 ldn= ((i) < 7) ? L[(i)+1]  : LDv; \
      u64 ru = ((i) > 0) ? Rr[(i)-1] : RUv; \
      u64 rdn= ((i) < 7) ? Rr[(i)+1] : RDv; \
      u64 nb = HROW(mu,lu,ru) | HROW(Sv,L[i],Rr[i]) | HROW(md,ldn,rdn); \
      u64 gg = Sv | (Pr[i] & nb); \
      if (gg != Sv){ \
        u64 ns = ks_flood(gg, Pr[i]); \
        Sr[i] = ns; sS[(r0+(i))*9+w] = ns; changed = true; \
      } \
    } \
  } while(0)

// ---------------- k_mid: hysteresis (blocks 0-15) || hist from comb (blocks 16-527) ----------------
__global__ void __launch_bounds__(512) k_mid(const u64* __restrict__ A, u64* __restrict__ S,
                                             const uint16_t* __restrict__ comb,
                                             uint32_t* __restrict__ hist)
{
  __shared__ __align__(16) char smem[512*9*8];   // 36864 B union
  __shared__ int wfl[2][12];
  int tid = threadIdx.x;
  if (blockIdx.x < 16){
    u64* sS = (u64*)smem;
    int img = blockIdx.x;
    const u64* gA = A + img * 4096;
    u64*       gS = S + img * 4096;
    for (int i = tid; i < 4096; i += 512)
      sS[(i>>3)*9 + (i&7)] = gS[i];
    if (tid < 12){ wfl[0][tid] = (tid >= 1 && tid <= 8) ? 1 : 0; wfl[1][tid] = 0; }
    __syncthreads();
    int  w    = tid & 7;
    int  g    = tid >> 3;
    int  r0   = g << 3;
    int  wvi  = tid >> 6;
    bool left = (w > 0), right = (w < 7);
    bool topw = ((g & 7) != 0), botw = ((g & 7) != 7);
    bool topi = (r0 > 0),       boti = (r0 < 504);
    u64 Sr[8], Pr[8];
    #pragma unroll
    for (int i = 0; i < 8; i++){
      Sr[i] = sS[(r0+i)*9 + w];
      Pr[i] = gA[(r0+i)*8 + w] | Sr[i];
    }
    int pb = 0, cb = 1;
    for (;;){
      bool act = (wfl[pb][wvi] | wfl[pb][wvi+1] | wfl[pb][wvi+2]) != 0;
      bool changed = false;
      if (act){
        #pragma unroll 1
        for (int rep = 0; rep < 2; rep++){
          u64 L[8], Rr[8];
          #pragma unroll
          for (int i = 0; i < 8; i++){
            u64 lv = __shfl_up(Sr[i], 1);
            u64 rv = __shfl_down(Sr[i], 1);
            L[i]  = left  ? lv : 0ull;
            Rr[i] = right ? rv : 0ull;
          }
          u64 t7  = __shfl_up(Sr[7], 8);
          u64 t7l = __shfl_up(Sr[7], 9);
          u64 t7r = __shfl_up(Sr[7], 7);
          u64 b0  = __shfl_down(Sr[0], 8);
          u64 b0l = __shfl_down(Sr[0], 7);
          u64 b0r = __shfl_down(Sr[0], 9);
          u64 MU, LUv, RUv, MD, LDv, RDv;
          if (topw){      MU = t7; LUv = left ? t7l : 0ull; RUv = right ? t7r : 0ull; }
          else if (topi){ MU = sS[(r0-1)*9+w];
                          LUv = left  ? sS[(r0-1)*9+w-1] : 0ull;
                          RUv = right ? sS[(r0-1)*9+w+1] : 0ull; }
          else { MU = 0ull; LUv = 0ull; RUv = 0ull; }
          if (botw){      MD = b0; LDv = left ? b0l : 0ull; RDv = right ? b0r : 0ull; }
          else if (boti){ MD = sS[(r0+8)*9+w];
                          LDv = left  ? sS[(r0+8)*9+w-1] : 0ull;
                          RDv = right ? sS[(r0+8)*9+w+1] : 0ull; }
          else { MD = 0ull; LDv = 0ull; RDv = 0ull; }
          #pragma unroll
          for (int i = 0; i < 8; i++) UPD2(i);
          #pragma unroll
          for (int i = 7; i >= 0; i--) UPD2(i);
        }
        if (changed) wfl[cb][wvi+1] = 1;
      }
      __syncthreads();
      if (tid == (wvi << 6)) wfl[pb][wvi+1] = 0;
      if (!__syncthreads_or(changed ? 1 : 0)) break;
      int ts = pb; pb = cb; cb = ts;
    }
    #pragma unroll
    for (int i = 0; i < 8; i++) gS[(r0+i)*8 + w] = Sr[i];
  } else {
    uint32_t* h = (uint32_t*)smem;
    int pb  = blockIdx.x - 16;
    int img = pb >> 5;
    int base = (pb & 31) * 8192;
    for (int i = tid; i < NBINS; i += 512) h[i] = 0u;
    __syncthreads();
    const uint16_t* cb = comb + (size_t)img*HW;
    #pragma unroll
    for (int it = 0; it < 4; it++){
      int f4 = it*512 + tid;
      ushort4 cv = *(const ushort4*)(cb + base + f4*4);
      atomicAdd(&h[cv.x], 1u);
      atomicAdd(&h[cv.y], 1u);
      atomicAdd(&h[cv.z], 1u);
      atomicAdd(&h[cv.w], 1u);
    }
    __syncthreads();
    uint32_t* gh = hist + img * NBINS;
    for (int i = tid; i < NBINS; i += 512){ uint32_t v = h[i]; if (v) atomicAdd(&gh[i], v); }
  }
}

// ---------------- fused 11-tap blur from bitmask + min/max partials + LAST-BLOCK stats ----------------
__global__ void __launch_bounds__(256) k_b11(const u64* __restrict__ S, float* __restrict__ out,
                                             float2* __restrict__ part,
                                             const uint32_t* __restrict__ hist,
                                             uint32_t* __restrict__ stats,
                                             uint32_t* __restrict__ cnt)
{
#pragma clang fp contract(off)
  __shared__ u64 wds[74][3];
  __shared__ float hb[74][64];
  __shared__ float smn[4], smx[4];
  __shared__ int isLast;
  int b = blockIdx.x;
  int img = b >> 6;
  int t = b & 63;
  int y0 = (t >> 3) << 6;
  int tx = t & 7;
  int x0 = tx << 6;
  int tid = threadIdx.x;
  float g[11]; { float s=0.0f; for(int i=0;i<11;i++){ float tt=(float)i-5.0f; g[i]=expf(-(tt*tt)/4.5f); s+=g[i]; } for(int i=0;i<11;i++) g[i]/=s; }
  for (int i = tid; i < 74*3; i += 256){
    int j = i/3, widx = i - j*3;
    int gy = refl(y0 - 5 + j, HH);
    int gw = tx - 1 + widx;
    wds[j][widx] = (gw >= 0 && gw < 8) ? S[img*4096 + gy*8 + gw] : 0ull;
  }
  __syncthreads();
  for (int i = tid; i < 74*64; i += 256){
    int j = i >> 6, c = i & 63;
    float acc = 0.0f;
    for (int k = 0; k < 11; k++){
      int xx = refl(x0 + c + k - 5, WW);
      int widx = (xx >> 6) - tx + 1;
      float bv = (float)((wds[j][widx] >> (xx & 63)) & 1ull);
      acc += g[k] * bv;
    }
    hb[j][c] = acc;
  }
  __syncthreads();
  float mn = 3.4e38f, mx = -3.4e38f;
  float* ob = out + (size_t)img*HW;
  for (int i = tid; i < 4096; i += 256){
    int y = i >> 6, c = i & 63;
    float acc = 0.0f;
    for (int k = 0; k < 11; k++) acc += g[k] * hb[y + k][c];
    ob[(y0 + y)*WW + x0 + c] = acc;
    mn = fminf(mn, acc); mx = fmaxf(mx, acc);
  }
  for (int off = 32; off >= 1; off >>= 1){
    mn = fminf(mn, __shfl_down(mn, off));
    mx = fmaxf(mx, __shfl_down(mx, off));
  }
  int wv = tid >> 6, ln = tid & 63;
  if (ln == 0){ smn[wv] = mn; smx[wv] = mx; }
  __syncthreads();
  if (tid == 0){
    part[b] = make_float2(fminf(fminf(smn[0],smn[1]),fminf(smn[2],smn[3])),
                          fmaxf(fmaxf(smx[0],smx[1]),fmaxf(smx[2],smx[3])));
    __threadfence();                                  // partials visible before count
    uint32_t prev = atomicAdd(&cnt[img], 1u);
    isLast = (prev == 63u) ? 1 : 0;
  }
  __syncthreads();
  if (isLast){
    // ---- per-image stats (former k_edred), run by the last finishing block ----
    __shared__ uint32_t sx[4], sn[4];
    uint32_t hmx = 0u, hmn = 0xFFFFFFFFu;
    for (int i = tid; i < NBINS; i += 256){
      uint32_t c = hist[img*NBINS + i];
      if (c > hmx) hmx = c;
      if (c > 0u && c < hmn) hmn = c;
    }
    for (int off = 32; off >= 1; off >>= 1){
      uint32_t ox = (uint32_t)__shfl_down((int)hmx, off);
      uint32_t on = (uint32_t)__shfl_down((int)hmn, off);
      if (ox > hmx) hmx = ox;
      if (on < hmn) hmn = on;
    }
    if (ln == 0){ sx[wv] = hmx; sn[wv] = hmn; }
    float fmn = 3.4e38f, fmx = -3.4e38f;
    if (wv == 0){
      float2 v = part[img*64 + ln];
      fmn = v.x; fmx = v.y;
      for (int off = 32; off >= 1; off >>= 1){
        fmn = fminf(fmn, __shfl_down(fmn, off));
        fmx = fmaxf(fmx, __shfl_down(fmx, off));
      }
    }
    __syncthreads();
    if (tid == 0){
      uint32_t MX = max(max(sx[0],sx[1]), max(sx[2],sx[3]));
      uint32_t MN = min(min(sn[0],sn[1]), min(sn[2],sn[3]));
      stats[img*4+0] = __float_as_uint(fmn);
      stats[img*4+1] = __float_as_uint(fmx);
      stats[img*4+2] = __float_as_uint(-logf((float)MX / 262144.0f + 1e-9f));
      stats[img*4+3] = __float_as_uint(-logf((float)MN / 262144.0f + 1e-9f));
    }
  }
}

// ---------------- fuse: normalize both maps, sigmoid (4 px/thread) ----------------
__global__ void __launch_bounds__(256) k_final(const float* __restrict__ ed,
                        const uint16_t* __restrict__ comb,
                        const uint32_t* __restrict__ hist, const uint32_t* __restrict__ stats,
                        const float* __restrict__ alpha, const float* __restrict__ beta,
                        float* __restrict__ out)
{
#pragma clang fp contract(off)
  int idx = blockIdx.x * 256 + threadIdx.x;      // float4 units
  int img = idx >> 16;
  float a = alpha[0], b = beta[0];
  float mne = __uint_as_float(stats[img*4+0]);
  float mxe = __uint_as_float(stats[img*4+1]);
  float mns = __uint_as_float(stats[img*4+2]);
  float mxs = __uint_as_float(stats[img*4+3]);
  float4 e4 = *(const float4*)(ed + (size_t)idx*4);
  ushort4 c4 = *(const ushort4*)(comb + (size_t)idx*4);
  const uint32_t* gh = hist + img*NBINS;
  float ee[4] = {e4.x, e4.y, e4.z, e4.w};
  uint16_t cc[4] = {c4.x, c4.y, c4.z, c4.w};
  float oo[4];
  #pragma unroll
  for (int j = 0; j < 4; j++){
    float sp = -logf((float)gh[cc[j]] / 262144.0f + 1e-9f);
    float en = (ee[j] - mne) / (mxe - mne + 1e-9f);
    float sn = (sp - mns) / (mxs - mns + 1e-9f);
    float f  = a*en + b*sn;
    oo[j] = 1.0f / (1.0f + expf(-f));
  }
  *(float4*)(out + (size_t)idx*4) = make_float4(oo[0], oo[1], oo[2], oo[3]);
}

extern "C" void kernel_launch(void* const* d_in, const int* in_sizes, int n_in,
                              void* d_out, int out_size, void* d_ws, size_t ws_size,
                              hipStream_t stream)
{
  const float* x     = (const float*)d_in[0];
  const float* mean  = (const float*)d_in[1];
  const float* stdv  = (const float*)d_in[2];
  const float* alpha = (const float*)d_in[3];
  const float* beta  = (const float*)d_in[4];
  float* out = (float*)d_out;

  char* ws = (char*)d_ws;
  float*    gray  = (float*)ws;                             // 16 MB
  uint16_t* comb  = (uint16_t*)(ws + (16u << 20));          // 8 MB
  float2*   part  = (float2*)(ws + (24u << 20));            // 8 KB
  uint32_t* hist  = (uint32_t*)(ws + (25u << 20));          // 256 KB
  u64*      Ab    = (u64*)(ws + (26u << 20));               // 512 KB
  u64*      Sb    = (u64*)(ws + (27u << 20));               // 512 KB
  uint32_t* stats = (uint32_t*)(ws + (28u << 20));          // 256 B
  uint32_t* cnt   = (uint32_t*)(ws + (28u << 20) + 4096);   // 64 B completion counters

  hipLaunchKernelGGL(k_gray,  dim3(1024),  dim3(256), 0, stream, x, mean, stdv, gray, comb, (uint4*)hist, cnt);
  hipLaunchKernelGGL(k_canny, dim3(2048),  dim3(256), 0, stream, gray, Ab, Sb);
  hipLaunchKernelGGL(k_mid,   dim3(528),   dim3(512), 0, stream, Ab, Sb, comb, hist);
  hipLaunchKernelGGL(k_b11,   dim3(1024),  dim3(256), 0, stream, Sb, out, part, hist, stats, cnt);
  hipLaunchKernelGGL(k_final, dim3(4096),  dim3(256), 0, stream, out, comb, hist, stats, alpha, beta, out);
}

// Round 16
// 117.975 us; speedup vs baseline: 1.1585x; 1.1585x over previous
//
#include <hip/hip_runtime.h>
#include <stdint.h>

#define NB 16
#define HH 512
#define WW 512
#define HW (HH*WW)          // 262144
#define NBINS 4096

typedef unsigned long long u64;

__device__ __forceinline__ float clip01(float v){ return fminf(fmaxf(v, 0.0f), 1.0f); }
__device__ __forceinline__ int refl(int i, int n){ if (i < 0) i = -i; if (i >= n) i = 2*n - 2 - i; return i; }
__device__ __forceinline__ int clampi(int i, int lo, int hi){ return i < lo ? lo : (i > hi ? hi : i); }

// ---------------- gray + comb (vectorized), also zeroes hist ----------------
__global__ void __launch_bounds__(256) k_gray(const float* __restrict__ x,
                                              const float* __restrict__ mean,
                                              const float* __restrict__ stdv,
                                              float* __restrict__ gray,
                                              uint16_t* __restrict__ comb,
                                              uint4* __restrict__ hist4)
{
#pragma clang fp contract(off)
  int b = blockIdx.x, tid = threadIdx.x;
  if (b < 64) hist4[b*256 + tid] = make_uint4(0u,0u,0u,0u);   // 256 KB hist zero
  int img  = b >> 6;
  int base = (b & 63) * 4096;
  float m0 = mean[0], m1 = mean[1], m2 = mean[2];
  float s0 = stdv[0], s1 = stdv[1], s2 = stdv[2];
  const float* xb = x + (size_t)img * 3 * HW;
  float*     gb   = gray + (size_t)img*HW;
  uint16_t*  cb   = comb + (size_t)img*HW;
  #pragma unroll
  for (int it = 0; it < 4; it++){
    int f4 = it*256 + tid;
    int p  = base + f4*4;
    float4 r = *(const float4*)(xb + p);
    float4 g = *(const float4*)(xb + HW + p);
    float4 bl= *(const float4*)(xb + 2*HW + p);
    float xr[4] = {r.x, r.y, r.z, r.w};
    float xg[4] = {g.x, g.y, g.z, g.w};
    float xbl[4] = {bl.x, bl.y, bl.z, bl.w};
    float gy[4]; uint16_t cc[4];
    #pragma unroll
    for (int j = 0; j < 4; j++){
      float cr = clip01(xr[j]*s0 + m0);
      float cg = clip01(xg[j]*s1 + m1);
      float cbv= clip01(xbl[j]*s2 + m2);
      gy[j] = 0.299f*cr + 0.587f*cg + 0.114f*cbv;
      int c = ((int)rintf(cr*15.0f))*256 + ((int)rintf(cg*15.0f))*16 + (int)rintf(cbv*15.0f);
      cc[j] = (uint16_t)c;
    }
    *(float4*)(gb + p) = make_float4(gy[0], gy[1], gy[2], gy[3]);
    ushort4 cv; cv.x = cc[0]; cv.y = cc[1]; cv.z = cc[2]; cv.w = cc[3];
    *(ushort4*)(cb + p) = cv;
  }
}

// ---------------- fused blur5 + sobel + NMS + threshold -> bitmasks ----------------
// 32x64 tile; sdir aliased into ubuf tail (mag uses 2278 of 2920 floats) -> 7 blocks/CU.
__global__ void __launch_bounds__(256) k_canny(const float* __restrict__ gray,
                                               u64* __restrict__ A, u64* __restrict__ Sb)
{
#pragma clang fp contract(off)
  __shared__ float ubuf[40*73];      // gray (40x72, s73); then mag (34x66, s67) in [0,2278) + sdir
  __shared__ float blr[36*69];       // blurred (36x68, s69)
  uint8_t* sdir = (uint8_t*)&ubuf[2278];
  int b = blockIdx.x;
  int img = b >> 7;
  int t = b & 127;
  int y0 = (t >> 3) << 5;
  int x0 = (t & 7) << 6;
  const float* gb = gray + (size_t)img*HW;
  int tid = threadIdx.x;
  float g5[5]; { float s=0.0f; for(int i=0;i<5;i++){ float tt=(float)i-2.0f; g5[i]=expf(-(tt*tt)/2.0f); s+=g5[i]; } for(int i=0;i<5;i++) g5[i]/=s; }
  // S1: load gray tile with reflect halo 4 (40 rows x 72 cols)
  for (int i = tid; i < 40*72; i += 256){
    int ly = i/72, lx = i - ly*72;
    int gy = refl(y0 - 4 + ly, HH);
    int gx = refl(x0 - 4 + lx, WW);
    ubuf[ly*73 + lx] = gb[gy*WW + gx];
  }
  __syncthreads();
  // S2: 5x5 blur, register-window column sweep (68 cols x 4 chunks of 9 rows)
  for (int task = tid; task < 272; task += 256){
    int lx = task % 68;
    int ly = (task / 68) * 9;
    float w[5][5];
    #pragma unroll
    for (int j = 0; j < 4; j++)
      #pragma unroll
      for (int k = 0; k < 5; k++)
        w[j][k] = ubuf[(ly+j)*73 + lx + k];
    #pragma unroll
    for (int s = 0; s < 9; s++){
      #pragma unroll
      for (int k = 0; k < 5; k++) w[4][k] = ubuf[(ly+s+4)*73 + lx + k];
      float acc = 0.0f;
      #pragma unroll
      for (int ky = 0; ky < 5; ky++)
        #pragma unroll
        for (int kx = 0; kx < 5; kx++)
          acc += (g5[ky]*g5[kx]) * w[ky][kx];
      blr[(ly+s)*69 + lx] = acc;
      #pragma unroll
      for (int j = 0; j < 4; j++)
        #pragma unroll
        for (int k = 0; k < 5; k++) w[j][k] = w[j+1][k];
    }
  }
  __syncthreads();
  // S3: sobel (clamp pad) -> mag (34x66) + dir (32x64); ubuf becomes mag
  for (int i = tid; i < 34*66; i += 256){
    int ly = i/66, lx = i - ly*66;
    int Y = y0 - 1 + ly, X = x0 - 1 + lx;
    float m = 0.0f;
    if (Y >= 0 && Y < HH && X >= 0 && X < WW){
      float v[3][3];
      for (int dy = 0; dy < 3; dy++){
        int Yl = clampi(Y + dy - 1, 0, HH-1) - (y0 - 2);
        for (int dx = 0; dx < 3; dx++){
          int Xl = clampi(X + dx - 1, 0, WW-1) - (x0 - 2);
          v[dy][dx] = blr[Yl*69 + Xl];
        }
      }
      float gx = (v[0][2] - v[0][0]) + 2.0f*(v[1][2] - v[1][0]) + (v[2][2] - v[2][0]);
      float gy = (v[2][0] + 2.0f*v[2][1] + v[2][2]) - (v[0][0] + 2.0f*v[0][1] + v[0][2]);
      m = sqrtf(gx*gx + gy*gy + 1e-6f);
      if (ly >= 1 && ly <= 32 && lx >= 1 && lx <= 64){
        float ax = fabsf(gx), ay = fabsf(gy);
        int d;
        if (ay <= 0.41421356237309503f*ax) d = (gx >= 0.0f) ? 0 : 4;
        else if (ay >= 2.4142135623730951f*ax) d = (gy > 0.0f) ? 2 : 6;
        else if (gx > 0.0f) d = (gy > 0.0f) ? 1 : 7;
        else d = (gy > 0.0f) ? 3 : 5;
        sdir[(ly-1)*64 + (lx-1)] = (uint8_t)d;
      }
    }
    ubuf[ly*67 + lx] = m;
  }
  __syncthreads();
  // S4: NMS + double threshold + ballot
  const int OY[8] = {0,1,1,1,0,-1,-1,-1};
  const int OX[8] = {1,1,0,-1,-1,-1,0,1};
  int lane = tid & 63, wv = tid >> 6;
  for (int j = 0; j < 8; j++){
    int y = j*4 + wv;
    int xx0 = lane;
    float m = ubuf[(y+1)*67 + (xx0+1)];
    int d  = sdir[y*64 + xx0];
    int d2 = (d + 4) & 7;
    float mp = 0.0f, mn = 0.0f;
    { int yy=y+OY[d],  xx=xx0+OX[d];  int gy=y0+yy, gx=x0+xx; if(gy>=0&&gy<HH&&gx>=0&&gx<WW) mp = ubuf[(yy+1)*67 + (xx+1)]; }
    { int yy=y+OY[d2], xx=xx0+OX[d2]; int gy=y0+yy, gx=x0+xx; if(gy>=0&&gy<HH&&gx>=0&&gx<WW) mn = ubuf[(yy+1)*67 + (xx+1)]; }
    bool keep = ((m - mp) > 0.0f) && ((m - mn) > 0.0f);
    float mf = keep ? m : 0.0f;
    bool strong = mf > 0.2f;
    bool weak   = (mf > 0.1f) && !strong;
    u64 wb = __ballot(weak);
    u64 sb = __ballot(strong);
    if (lane == 0){
      int gy = y0 + y;
      A [img*4096 + gy*8 + (x0>>6)] = wb;
      Sb[img*4096 + gy*8 + (x0>>6)] = sb;
    }
  }
}

// ---------------- hysteresis helpers ----------------
__device__ __forceinline__ u64 ks_flood(u64 g, u64 P){
  u64 p1 = P, g1 = g;
  g1 |= p1 & (g1 << 1);  p1 &= (p1 << 1);
  g1 |= p1 & (g1 << 2);  p1 &= (p1 << 2);
  g1 |= p1 & (g1 << 4);  p1 &= (p1 << 4);
  g1 |= p1 & (g1 << 8);  p1 &= (p1 << 8);
  g1 |= p1 & (g1 << 16); p1 &= (p1 << 16);
  g1 |= p1 & (g1 << 32);
  u64 p2 = P, g2 = g;
  g2 |= p2 & (g2 >> 1);  p2 &= (p2 >> 1);
  g2 |= p2 & (g2 >> 2);  p2 &= (p2 >> 2);
  g2 |= p2 & (g2 >> 4);  p2 &= (p2 >> 4);
  g2 |= p2 & (g2 >> 8);  p2 &= (p2 >> 8);
  g2 |= p2 & (g2 >> 16); p2 &= (p2 >> 16);
  g2 |= p2 & (g2 >> 32);
  return g1 | g2;
}

#define HROW(m, l, r_) ((m) | ((m)<<1) | ((m)>>1) | ((l)>>63) | ((r_)<<63))

#define UPD2(i) do{ \
    if (Pr[i] & ~Sr[i]){ \
      u64 Sv = Sr[i]; \
      u64 mu = ((i) > 0) ? Sr[(i)-1] : MU; \
      u64 md = ((i) < 7) ? Sr[(i)+1] : MD; \
      u64 lu = ((i) > 0) ? L[(i)-1]  : LUv; \
      u64 ldn= ((i) < 7) ? L[(i)+1]  : LDv; \
      u64 ru = ((i) > 0) ? Rr[(i)-1] : RUv; \
      u64 rdn= ((i) < 7) ? Rr[(i)+1] : RDv; \
      u64 nb = HROW(mu,lu,ru) | HROW(Sv,L[i],Rr[i]) | HROW(md,ldn,rdn); \
      u64 gg = Sv | (Pr[i] & nb); \
      if (gg != Sv){ \
        u64 ns = ks_flood(gg, Pr[i]); \
        Sr[i] = ns; sS[(r0+(i))*9+w] = ns; changed = true; \
      } \
    } \
  } while(0)

// ---------------- k_mid: hysteresis (blocks 0-15) || hist from comb (blocks 16-527) ----------------
__global__ void __launch_bounds__(512) k_mid(const u64* __restrict__ A, u64* __restrict__ S,
                                             const uint16_t* __restrict__ comb,
                                             uint32_t* __restrict__ hist)
{
  __shared__ __align__(16) char smem[512*9*8];   // 36864 B union
  __shared__ int wfl[2][12];
  int tid = threadIdx.x;
  if (blockIdx.x < 16){
    u64* sS = (u64*)smem;
    int img = blockIdx.x;
    const u64* gA = A + img * 4096;
    u64*       gS = S + img * 4096;
    for (int i = tid; i < 4096; i += 512)
      sS[(i>>3)*9 + (i&7)] = gS[i];
    if (tid < 12){ wfl[0][tid] = (tid >= 1 && tid <= 8) ? 1 : 0; wfl[1][tid] = 0; }
    __syncthreads();
    int  w    = tid & 7;
    int  g    = tid >> 3;
    int  r0   = g << 3;
    int  wvi  = tid >> 6;
    bool left = (w > 0), right = (w < 7);
    bool topw = ((g & 7) != 0), botw = ((g & 7) != 7);
    bool topi = (r0 > 0),       boti = (r0 < 504);
    u64 Sr[8], Pr[8];
    #pragma unroll
    for (int i = 0; i < 8; i++){
      Sr[i] = sS[(r0+i)*9 + w];
      Pr[i] = gA[(r0+i)*8 + w] | Sr[i];
    }
    int pb = 0, cb = 1;
    for (;;){
      bool act = (wfl[pb][wvi] | wfl[pb][wvi+1] | wfl[pb][wvi+2]) != 0;
      bool changed = false;
      if (act){
        #pragma unroll 1
        for (int rep = 0; rep < 2; rep++){
          u64 L[8], Rr[8];
          #pragma unroll
          for (int i = 0; i < 8; i++){
            u64 lv = __shfl_up(Sr[i], 1);
            u64 rv = __shfl_down(Sr[i], 1);
            L[i]  = left  ? lv : 0ull;
            Rr[i] = right ? rv : 0ull;
          }
          u64 t7  = __shfl_up(Sr[7], 8);
          u64 t7l = __shfl_up(Sr[7], 9);
          u64 t7r = __shfl_up(Sr[7], 7);
          u64 b0  = __shfl_down(Sr[0], 8);
          u64 b0l = __shfl_down(Sr[0], 7);
          u64 b0r = __shfl_down(Sr[0], 9);
          u64 MU, LUv, RUv, MD, LDv, RDv;
          if (topw){      MU = t7; LUv = left ? t7l : 0ull; RUv = right ? t7r : 0ull; }
          else if (topi){ MU = sS[(r0-1)*9+w];
                          LUv = left  ? sS[(r0-1)*9+w-1] : 0ull;
                          RUv = right ? sS[(r0-1)*9+w+1] : 0ull; }
          else { MU = 0ull; LUv = 0ull; RUv = 0ull; }
          if (botw){      MD = b0; LDv = left ? b0l : 0ull; RDv = right ? b0r : 0ull; }
          else if (boti){ MD = sS[(r0+8)*9+w];
                          LDv = left  ? sS[(r0+8)*9+w-1] : 0ull;
                          RDv = right ? sS[(r0+8)*9+w+1] : 0ull; }
          else { MD = 0ull; LDv = 0ull; RDv = 0ull; }
          #pragma unroll
          for (int i = 0; i < 8; i++) UPD2(i);
          #pragma unroll
          for (int i = 7; i >= 0; i--) UPD2(i);
        }
        if (changed) wfl[cb][wvi+1] = 1;
      }
      __syncthreads();
      if (tid == (wvi << 6)) wfl[pb][wvi+1] = 0;
      if (!__syncthreads_or(changed ? 1 : 0)) break;
      int ts = pb; pb = cb; cb = ts;
    }
    #pragma unroll
    for (int i = 0; i < 8; i++) gS[(r0+i)*8 + w] = Sr[i];
  } else {
    uint32_t* h = (uint32_t*)smem;
    int pb  = blockIdx.x - 16;
    int img = pb >> 5;
    int base = (pb & 31) * 8192;
    for (int i = tid; i < NBINS; i += 512) h[i] = 0u;
    __syncthreads();
    const uint16_t* cb = comb + (size_t)img*HW;
    #pragma unroll
    for (int it = 0; it < 4; it++){
      int f4 = it*512 + tid;
      ushort4 cv = *(const ushort4*)(cb + base + f4*4);
      atomicAdd(&h[cv.x], 1u);
      atomicAdd(&h[cv.y], 1u);
      atomicAdd(&h[cv.z], 1u);
      atomicAdd(&h[cv.w], 1u);
    }
    __syncthreads();
    uint32_t* gh = hist + img * NBINS;
    for (int i = tid; i < NBINS; i += 512){ uint32_t v = h[i]; if (v) atomicAdd(&gh[i], v); }
  }
}

// ---------------- fused 11-tap separable blur from bitmask + min/max partials ----------------
__global__ void __launch_bounds__(256) k_b11(const u64* __restrict__ S, float* __restrict__ out,
                                             float2* __restrict__ part)
{
#pragma clang fp contract(off)
  __shared__ u64 wds[74][3];
  __shared__ float hb[74][64];
  __shared__ float smn[4], smx[4];
  int b = blockIdx.x;
  int img = b >> 6;
  int t = b & 63;
  int y0 = (t >> 3) << 6;
  int tx = t & 7;
  int x0 = tx << 6;
  int tid = threadIdx.x;
  float g[11]; { float s=0.0f; for(int i=0;i<11;i++){ float tt=(float)i-5.0f; g[i]=expf(-(tt*tt)/4.5f); s+=g[i]; } for(int i=0;i<11;i++) g[i]/=s; }
  for (int i = tid; i < 74*3; i += 256){
    int j = i/3, widx = i - j*3;
    int gy = refl(y0 - 5 + j, HH);
    int gw = tx - 1 + widx;
    wds[j][widx] = (gw >= 0 && gw < 8) ? S[img*4096 + gy*8 + gw] : 0ull;
  }
  __syncthreads();
  for (int i = tid; i < 74*64; i += 256){
    int j = i >> 6, c = i & 63;
    float acc = 0.0f;
    for (int k = 0; k < 11; k++){
      int xx = refl(x0 + c + k - 5, WW);
      int widx = (xx >> 6) - tx + 1;
      float bv = (float)((wds[j][widx] >> (xx & 63)) & 1ull);
      acc += g[k] * bv;
    }
    hb[j][c] = acc;
  }
  __syncthreads();
  float mn = 3.4e38f, mx = -3.4e38f;
  float* ob = out + (size_t)img*HW;
  for (int i = tid; i < 4096; i += 256){
    int y = i >> 6, c = i & 63;
    float acc = 0.0f;
    for (int k = 0; k < 11; k++) acc += g[k] * hb[y + k][c];
    ob[(y0 + y)*WW + x0 + c] = acc;
    mn = fminf(mn, acc); mx = fmaxf(mx, acc);
  }
  for (int off = 32; off >= 1; off >>= 1){
    mn = fminf(mn, __shfl_down(mn, off));
    mx = fmaxf(mx, __shfl_down(mx, off));
  }
  int wv = tid >> 6, ln = tid & 63;
  if (ln == 0){ smn[wv] = mn; smx[wv] = mx; }
  __syncthreads();
  if (tid == 0){
    part[b] = make_float2(fminf(fminf(smn[0],smn[1]),fminf(smn[2],smn[3])),
                          fmaxf(fmaxf(smx[0],smx[1]),fmaxf(smx[2],smx[3])));
  }
}

// ---------------- edge min/max partials + sparsity min/max ----------------
__global__ void __launch_bounds__(256) k_edred(const float2* __restrict__ part,
                                               const uint32_t* __restrict__ hist,
                                               uint32_t* __restrict__ stats){
  __shared__ uint32_t sx[4], sn[4];
  int img = blockIdx.x;
  int tid = threadIdx.x;
  uint32_t mx = 0u, mn = 0xFFFFFFFFu;
  for (int i = tid; i < NBINS; i += 256){
    uint32_t c = hist[img*NBINS + i];
    if (c > mx) mx = c;
    if (c > 0u && c < mn) mn = c;
  }
  for (int off = 32; off >= 1; off >>= 1){
    uint32_t ox = (uint32_t)__shfl_down((int)mx, off);
    uint32_t on = (uint32_t)__shfl_down((int)mn, off);
    if (ox > mx) mx = ox;
    if (on < mn) mn = on;
  }
  int wv = tid >> 6, ln = tid & 63;
  if (ln == 0){ sx[wv] = mx; sn[wv] = mn; }
  float fmn = 3.4e38f, fmx = -3.4e38f;
  if (wv == 0){
    float2 v = part[img*64 + ln];
    fmn = v.x; fmx = v.y;
    for (int off = 32; off >= 1; off >>= 1){
      fmn = fminf(fmn, __shfl_down(fmn, off));
      fmx = fmaxf(fmx, __shfl_down(fmx, off));
    }
  }
  __syncthreads();
  if (tid == 0){
    uint32_t MX = max(max(sx[0],sx[1]), max(sx[2],sx[3]));
    uint32_t MN = min(min(sn[0],sn[1]), min(sn[2],sn[3]));
    stats[img*4+0] = __float_as_uint(fmn);
    stats[img*4+1] = __float_as_uint(fmx);
    stats[img*4+2] = __float_as_uint(-logf((float)MX / 262144.0f + 1e-9f));
    stats[img*4+3] = __float_as_uint(-logf((float)MN / 262144.0f + 1e-9f));
  }
}

// ---------------- fuse: normalize both maps, sigmoid (4 px/thread) ----------------
__global__ void __launch_bounds__(256) k_final(const float* __restrict__ ed,
                        const uint16_t* __restrict__ comb,
                        const uint32_t* __restrict__ hist, const uint32_t* __restrict__ stats,
                        const float* __restrict__ alpha, const float* __restrict__ beta,
                        float* __restrict__ out)
{
#pragma clang fp contract(off)
  int idx = blockIdx.x * 256 + threadIdx.x;      // float4 units
  int img = idx >> 16;
  float a = alpha[0], b = beta[0];
  float mne = __uint_as_float(stats[img*4+0]);
  float mxe = __uint_as_float(stats[img*4+1]);
  float mns = __uint_as_float(stats[img*4+2]);
  float mxs = __uint_as_float(stats[img*4+3]);
  float4 e4 = *(const float4*)(ed + (size_t)idx*4);
  ushort4 c4 = *(const ushort4*)(comb + (size_t)idx*4);
  const uint32_t* gh = hist + img*NBINS;
  float ee[4] = {e4.x, e4.y, e4.z, e4.w};
  uint16_t cc[4] = {c4.x, c4.y, c4.z, c4.w};
  float oo[4];
  #pragma unroll
  for (int j = 0; j < 4; j++){
    float sp = -logf((float)gh[cc[j]] / 262144.0f + 1e-9f);
    float en = (ee[j] - mne) / (mxe - mne + 1e-9f);
    float sn = (sp - mns) / (mxs - mns + 1e-9f);
    float f  = a*en + b*sn;
    oo[j] = 1.0f / (1.0f + expf(-f));
  }
  *(float4*)(out + (size_t)idx*4) = make_float4(oo[0], oo[1], oo[2], oo[3]);
}

extern "C" void kernel_launch(void* const* d_in, const int* in_sizes, int n_in,
                              void* d_out, int out_size, void* d_ws, size_t ws_size,
                              hipStream_t stream)
{
  const float* x     = (const float*)d_in[0];
  const float* mean  = (const float*)d_in[1];
  const float* stdv  = (const float*)d_in[2];
  const float* alpha = (const float*)d_in[3];
  const float* beta  = (const float*)d_in[4];
  float* out = (float*)d_out;

  char* ws = (char*)d_ws;
  float*    gray  = (float*)ws;                             // 16 MB
  uint16_t* comb  = (uint16_t*)(ws + (16u << 20));          // 8 MB
  float2*   part  = (float2*)(ws + (24u << 20));            // 8 KB
  uint32_t* hist  = (uint32_t*)(ws + (25u << 20));          // 256 KB
  u64*      Ab    = (u64*)(ws + (26u << 20));               // 512 KB
  u64*      Sb    = (u64*)(ws + (27u << 20));               // 512 KB
  uint32_t* stats = (uint32_t*)(ws + (28u << 20));          // 256 B

  hipLaunchKernelGGL(k_gray,  dim3(1024),  dim3(256), 0, stream, x, mean, stdv, gray, comb, (uint4*)hist);
  hipLaunchKernelGGL(k_canny, dim3(2048),  dim3(256), 0, stream, gray, Ab, Sb);
  hipLaunchKernelGGL(k_mid,   dim3(528),   dim3(512), 0, stream, Ab, Sb, comb, hist);
  hipLaunchKernelGGL(k_b11,   dim3(1024),  dim3(256), 0, stream, Sb, out, part);
  hipLaunchKernelGGL(k_edred, dim3(NB),    dim3(256), 0, stream, part, hist, stats);
  hipLaunchKernelGGL(k_final, dim3(4096),  dim3(256), 0, stream, out, comb, hist, stats, alpha, beta, out);
}

// Round 17
// 113.859 us; speedup vs baseline: 1.2003x; 1.0362x over previous
//
#include <hip/hip_runtime.h>
#include <stdint.h>

#define NB 16
#define HH 512
#define WW 512
#define HW (HH*WW)          // 262144
#define NBINS 4096

typedef unsigned long long u64;

__device__ __forceinline__ float clip01(float v){ return fminf(fmaxf(v, 0.0f), 1.0f); }
__device__ __forceinline__ int refl(int i, int n){ if (i < 0) i = -i; if (i >= n) i = 2*n - 2 - i; return i; }
__device__ __forceinline__ int clampi(int i, int lo, int hi){ return i < lo ? lo : (i > hi ? hi : i); }

// ---------------- hysteresis helpers (shared by k_canny local flood + k_mid) ----------------
__device__ __forceinline__ u64 ks_flood(u64 g, u64 P){
  u64 p1 = P, g1 = g;
  g1 |= p1 & (g1 << 1);  p1 &= (p1 << 1);
  g1 |= p1 & (g1 << 2);  p1 &= (p1 << 2);
  g1 |= p1 & (g1 << 4);  p1 &= (p1 << 4);
  g1 |= p1 & (g1 << 8);  p1 &= (p1 << 8);
  g1 |= p1 & (g1 << 16); p1 &= (p1 << 16);
  g1 |= p1 & (g1 << 32);
  u64 p2 = P, g2 = g;
  g2 |= p2 & (g2 >> 1);  p2 &= (p2 >> 1);
  g2 |= p2 & (g2 >> 2);  p2 &= (p2 >> 2);
  g2 |= p2 & (g2 >> 4);  p2 &= (p2 >> 4);
  g2 |= p2 & (g2 >> 8);  p2 &= (p2 >> 8);
  g2 |= p2 & (g2 >> 16); p2 &= (p2 >> 16);
  g2 |= p2 & (g2 >> 32);
  return g1 | g2;
}

#define HROW(m, l, r_) ((m) | ((m)<<1) | ((m)>>1) | ((l)>>63) | ((r_)<<63))

// ---------------- gray + comb (vectorized), also zeroes hist ----------------
__global__ void __launch_bounds__(256) k_gray(const float* __restrict__ x,
                                              const float* __restrict__ mean,
                                              const float* __restrict__ stdv,
                                              float* __restrict__ gray,
                                              uint16_t* __restrict__ comb,
                                              uint4* __restrict__ hist4)
{
#pragma clang fp contract(off)
  int b = blockIdx.x, tid = threadIdx.x;
  if (b < 64) hist4[b*256 + tid] = make_uint4(0u,0u,0u,0u);   // 256 KB hist zero
  int img  = b >> 6;
  int base = (b & 63) * 4096;
  float m0 = mean[0], m1 = mean[1], m2 = mean[2];
  float s0 = stdv[0], s1 = stdv[1], s2 = stdv[2];
  const float* xb = x + (size_t)img * 3 * HW;
  float*     gb   = gray + (size_t)img*HW;
  uint16_t*  cb   = comb + (size_t)img*HW;
  #pragma unroll
  for (int it = 0; it < 4; it++){
    int f4 = it*256 + tid;
    int p  = base + f4*4;
    float4 r = *(const float4*)(xb + p);
    float4 g = *(const float4*)(xb + HW + p);
    float4 bl= *(const float4*)(xb + 2*HW + p);
    float xr[4] = {r.x, r.y, r.z, r.w};
    float xg[4] = {g.x, g.y, g.z, g.w};
    float xbl[4] = {bl.x, bl.y, bl.z, bl.w};
    float gy[4]; uint16_t cc[4];
    #pragma unroll
    for (int j = 0; j < 4; j++){
      float cr = clip01(xr[j]*s0 + m0);
      float cg = clip01(xg[j]*s1 + m1);
      float cbv= clip01(xbl[j]*s2 + m2);
      gy[j] = 0.299f*cr + 0.587f*cg + 0.114f*cbv;
      int c = ((int)rintf(cr*15.0f))*256 + ((int)rintf(cg*15.0f))*16 + (int)rintf(cbv*15.0f);
      cc[j] = (uint16_t)c;
    }
    *(float4*)(gb + p) = make_float4(gy[0], gy[1], gy[2], gy[3]);
    ushort4 cv; cv.x = cc[0]; cv.y = cc[1]; cv.z = cc[2]; cv.w = cc[3];
    *(ushort4*)(cb + p) = cv;
  }
}

// ---------------- fused blur5 + sobel + NMS + threshold + LOCAL hysteresis -> bitmasks ----------------
// 32x64 tile; sdir aliased into ubuf tail. After thresholding, a tile-local
// hysteresis flood (32 u64 words, wave 0) promotes intra-tile weak chains —
// a lower bound of the global fixpoint (monotone OR-propagation, subset of
// neighbors), so k_mid converges in fewer rounds with identical final masks.
__global__ void __launch_bounds__(256) k_canny(const float* __restrict__ gray,
                                               u64* __restrict__ A, u64* __restrict__ Sb)
{
#pragma clang fp contract(off)
  __shared__ float ubuf[40*73];      // gray (40x72, s73); then mag (34x66, s67) in [0,2278) + sdir
  __shared__ float blr[36*69];       // blurred (36x68, s69); tail reused for mask words in S4/S5
  uint8_t* sdir = (uint8_t*)&ubuf[2278];
  u64* sAw = (u64*)blr;              // 32 u64 (blr dead after S3)
  u64* sSw = (u64*)blr + 32;         // 32 u64
  int b = blockIdx.x;
  int img = b >> 7;
  int t = b & 127;
  int y0 = (t >> 3) << 5;
  int x0 = (t & 7) << 6;
  const float* gb = gray + (size_t)img*HW;
  int tid = threadIdx.x;
  float g5[5]; { float s=0.0f; for(int i=0;i<5;i++){ float tt=(float)i-2.0f; g5[i]=expf(-(tt*tt)/2.0f); s+=g5[i]; } for(int i=0;i<5;i++) g5[i]/=s; }
  // S1: load gray tile with reflect halo 4 (40 rows x 72 cols)
  for (int i = tid; i < 40*72; i += 256){
    int ly = i/72, lx = i - ly*72;
    int gy = refl(y0 - 4 + ly, HH);
    int gx = refl(x0 - 4 + lx, WW);
    ubuf[ly*73 + lx] = gb[gy*WW + gx];
  }
  __syncthreads();
  // S2: 5x5 blur, register-window column sweep (68 cols x 4 chunks of 9 rows)
  for (int task = tid; task < 272; task += 256){
    int lx = task % 68;
    int ly = (task / 68) * 9;
    float w[5][5];
    #pragma unroll
    for (int j = 0; j < 4; j++)
      #pragma unroll
      for (int k = 0; k < 5; k++)
        w[j][k] = ubuf[(ly+j)*73 + lx + k];
    #pragma unroll
    for (int s = 0; s < 9; s++){
      #pragma unroll
      for (int k = 0; k < 5; k++) w[4][k] = ubuf[(ly+s+4)*73 + lx + k];
      float acc = 0.0f;
      #pragma unroll
      for (int ky = 0; ky < 5; ky++)
        #pragma unroll
        for (int kx = 0; kx < 5; kx++)
          acc += (g5[ky]*g5[kx]) * w[ky][kx];
      blr[(ly+s)*69 + lx] = acc;
      #pragma unroll
      for (int j = 0; j < 4; j++)
        #pragma unroll
        for (int k = 0; k < 5; k++) w[j][k] = w[j+1][k];
    }
  }
  __syncthreads();
  // S3: sobel (clamp pad) -> mag (34x66) + dir (32x64); ubuf becomes mag
  for (int i = tid; i < 34*66; i += 256){
    int ly = i/66, lx = i - ly*66;
    int Y = y0 - 1 + ly, X = x0 - 1 + lx;
    float m = 0.0f;
    if (Y >= 0 && Y < HH && X >= 0 && X < WW){
      float v[3][3];
      for (int dy = 0; dy < 3; dy++){
        int Yl = clampi(Y + dy - 1, 0, HH-1) - (y0 - 2);
        for (int dx = 0; dx < 3; dx++){
          int Xl = clampi(X + dx - 1, 0, WW-1) - (x0 - 2);
          v[dy][dx] = blr[Yl*69 + Xl];
        }
      }
      float gx = (v[0][2] - v[0][0]) + 2.0f*(v[1][2] - v[1][0]) + (v[2][2] - v[2][0]);
      float gy = (v[2][0] + 2.0f*v[2][1] + v[2][2]) - (v[0][0] + 2.0f*v[0][1] + v[0][2]);
      m = sqrtf(gx*gx + gy*gy + 1e-6f);
      if (ly >= 1 && ly <= 32 && lx >= 1 && lx <= 64){
        float ax = fabsf(gx), ay = fabsf(gy);
        int d;
        if (ay <= 0.41421356237309503f*ax) d = (gx >= 0.0f) ? 0 : 4;
        else if (ay >= 2.4142135623730951f*ax) d = (gy > 0.0f) ? 2 : 6;
        else if (gx > 0.0f) d = (gy > 0.0f) ? 1 : 7;
        else d = (gy > 0.0f) ? 3 : 5;
        sdir[(ly-1)*64 + (lx-1)] = (uint8_t)d;
      }
    }
    ubuf[ly*67 + lx] = m;
  }
  __syncthreads();
  // S4: NMS + double threshold + ballot -> LDS mask words (A written to global directly)
  const int OY[8] = {0,1,1,1,0,-1,-1,-1};
  const int OX[8] = {1,1,0,-1,-1,-1,0,1};
  int lane = tid & 63, wv = tid >> 6;
  for (int j = 0; j < 8; j++){
    int y = j*4 + wv;
    int xx0 = lane;
    float m = ubuf[(y+1)*67 + (xx0+1)];
    int d  = sdir[y*64 + xx0];
    int d2 = (d + 4) & 7;
    float mp = 0.0f, mn = 0.0f;
    { int yy=y+OY[d],  xx=xx0+OX[d];  int gy=y0+yy, gx=x0+xx; if(gy>=0&&gy<HH&&gx>=0&&gx<WW) mp = ubuf[(yy+1)*67 + (xx+1)]; }
    { int yy=y+OY[d2], xx=xx0+OX[d2]; int gy=y0+yy, gx=x0+xx; if(gy>=0&&gy<HH&&gx>=0&&gx<WW) mn = ubuf[(yy+1)*67 + (xx+1)]; }
    bool keep = ((m - mp) > 0.0f) && ((m - mn) > 0.0f);
    float mf = keep ? m : 0.0f;
    bool strong = mf > 0.2f;
    bool weak   = (mf > 0.1f) && !strong;
    u64 wb = __ballot(weak);
    u64 sb = __ballot(strong);
    if (lane == 0){
      A[img*4096 + (y0 + y)*8 + (x0>>6)] = wb;
      sAw[y] = wb;
      sSw[y] = sb;
    }
  }
  __syncthreads();
  // S5: tile-local hysteresis flood (wave 0, 32 rows x 1 word) -> promoted strong to global
  if (tid < 32){
    int r = tid;
    u64 P = sAw[r] | sSw[r];
    u64 S = sSw[r];
    for (;;){
      u64 mu = __shfl_up(S, 1);   if (r == 0)  mu = 0ull;
      u64 md = __shfl_down(S, 1); if (r == 31) md = 0ull;
      u64 nb = HROW(mu,0ull,0ull) | HROW(S,0ull,0ull) | HROW(md,0ull,0ull);
      u64 g = S | (P & nb);
      bool ch = false;
      if (g != S){
        u64 ns = ks_flood(g, P);
        if (ns != S){ S = ns; ch = true; }
      }
      if (!__any(ch ? 1 : 0)) break;
    }
    Sb[img*4096 + (y0 + r)*8 + (x0>>6)] = S;
  }
}

#define UPD2(i) do{ \
    if (Pr[i] & ~Sr[i]){ \
      u64 Sv = Sr[i]; \
      u64 mu = ((i) > 0) ? Sr[(i)-1] : MU; \
      u64 md = ((i) < 7) ? Sr[(i)+1] : MD; \
      u64 lu = ((i) > 0) ? L[(i)-1]  : LUv; \
      u64 ldn= ((i) < 7) ? L[(i)+1]  : LDv; \
      u64 ru = ((i) > 0) ? Rr[(i)-1] : RUv; \
      u64 rdn= ((i) < 7) ? Rr[(i)+1] : RDv; \
      u64 nb = HROW(mu,lu,ru) | HROW(Sv,L[i],Rr[i]) | HROW(md,ldn,rdn); \
      u64 gg = Sv | (Pr[i] & nb); \
      if (gg != Sv){ \
        u64 ns = ks_flood(gg, Pr[i]); \
        Sr[i] = ns; sS[(r0+(i))*9+w] = ns; changed = true; \
      } \
    } \
  } while(0)

// ---------------- k_mid: hysteresis (blocks 0-15) || hist from comb (blocks 16-527) ----------------
__global__ void __launch_bounds__(512) k_mid(const u64* __restrict__ A, u64* __restrict__ S,
                                             const uint16_t* __restrict__ comb,
                                             uint32_t* __restrict__ hist)
{
  __shared__ __align__(16) char smem[512*9*8];   // 36864 B union
  __shared__ int wfl[2][12];
  int tid = threadIdx.x;
  if (blockIdx.x < 16){
    u64* sS = (u64*)smem;
    int img = blockIdx.x;
    const u64* gA = A + img * 4096;
    u64*       gS = S + img * 4096;
    for (int i = tid; i < 4096; i += 512)
      sS[(i>>3)*9 + (i&7)] = gS[i];
    if (tid < 12){ wfl[0][tid] = (tid >= 1 && tid <= 8) ? 1 : 0; wfl[1][tid] = 0; }
    __syncthreads();
    int  w    = tid & 7;
    int  g    = tid >> 3;
    int  r0   = g << 3;
    int  wvi  = tid >> 6;
    bool left = (w > 0), right = (w < 7);
    bool topw = ((g & 7) != 0), botw = ((g & 7) != 7);
    bool topi = (r0 > 0),       boti = (r0 < 504);
    u64 Sr[8], Pr[8];
    #pragma unroll
    for (int i = 0; i < 8; i++){
      Sr[i] = sS[(r0+i)*9 + w];
      Pr[i] = gA[(r0+i)*8 + w] | Sr[i];
    }
    int pb = 0, cb = 1;
    for (;;){
      bool act = (wfl[pb][wvi] | wfl[pb][wvi+1] | wfl[pb][wvi+2]) != 0;
      bool changed = false;
      if (act){
        #pragma unroll 1
        for (int rep = 0; rep < 2; rep++){
          u64 L[8], Rr[8];
          #pragma unroll
          for (int i = 0; i < 8; i++){
            u64 lv = __shfl_up(Sr[i], 1);
            u64 rv = __shfl_down(Sr[i], 1);
            L[i]  = left  ? lv : 0ull;
            Rr[i] = right ? rv : 0ull;
          }
          u64 t7  = __shfl_up(Sr[7], 8);
          u64 t7l = __shfl_up(Sr[7], 9);
          u64 t7r = __shfl_up(Sr[7], 7);
          u64 b0  = __shfl_down(Sr[0], 8);
          u64 b0l = __shfl_down(Sr[0], 7);
          u64 b0r = __shfl_down(Sr[0], 9);
          u64 MU, LUv, RUv, MD, LDv, RDv;
          if (topw){      MU = t7; LUv = left ? t7l : 0ull; RUv = right ? t7r : 0ull; }
          else if (topi){ MU = sS[(r0-1)*9+w];
                          LUv = left  ? sS[(r0-1)*9+w-1] : 0ull;
                          RUv = right ? sS[(r0-1)*9+w+1] : 0ull; }
          else { MU = 0ull; LUv = 0ull; RUv = 0ull; }
          if (botw){      MD = b0; LDv = left ? b0l : 0ull; RDv = right ? b0r : 0ull; }
          else if (boti){ MD = sS[(r0+8)*9+w];
                          LDv = left  ? sS[(r0+8)*9+w-1] : 0ull;
                          RDv = right ? sS[(r0+8)*9+w+1] : 0ull; }
          else { MD = 0ull; LDv = 0ull; RDv = 0ull; }
          #pragma unroll
          for (int i = 0; i < 8; i++) UPD2(i);
          #pragma unroll
          for (int i = 7; i >= 0; i--) UPD2(i);
        }
        if (changed) wfl[cb][wvi+1] = 1;
      }
      __syncthreads();
      if (tid == (wvi << 6)) wfl[pb][wvi+1] = 0;
      if (!__syncthreads_or(changed ? 1 : 0)) break;
      int ts = pb; pb = cb; cb = ts;
    }
    #pragma unroll
    for (int i = 0; i < 8; i++) gS[(r0+i)*8 + w] = Sr[i];
  } else {
    uint32_t* h = (uint32_t*)smem;
    int pb  = blockIdx.x - 16;
    int img = pb >> 5;
    int base = (pb & 31) * 8192;
    for (int i = tid; i < NBINS; i += 512) h[i] = 0u;
    __syncthreads();
    const uint16_t* cb = comb + (size_t)img*HW;
    #pragma unroll
    for (int it = 0; it < 4; it++){
      int f4 = it*512 + tid;
      ushort4 cv = *(const ushort4*)(cb + base + f4*4);
      atomicAdd(&h[cv.x], 1u);
      atomicAdd(&h[cv.y], 1u);
      atomicAdd(&h[cv.z], 1u);
      atomicAdd(&h[cv.w], 1u);
    }
    __syncthreads();
    uint32_t* gh = hist + img * NBINS;
    for (int i = tid; i < NBINS; i += 512){ uint32_t v = h[i]; if (v) atomicAdd(&gh[i], v); }
  }
}

// ---------------- fused 11-tap separable blur from bitmask + min/max partials ----------------
__global__ void __launch_bounds__(256) k_b11(const u64* __restrict__ S, float* __restrict__ out,
                                             float2* __restrict__ part)
{
#pragma clang fp contract(off)
  __shared__ u64 wds[74][3];
  __shared__ float hb[74][64];
  __shared__ float smn[4], smx[4];
  int b = blockIdx.x;
  int img = b >> 6;
  int t = b & 63;
  int y0 = (t >> 3) << 6;
  int tx = t & 7;
  int x0 = tx << 6;
  int tid = threadIdx.x;
  float g[11]; { float s=0.0f; for(int i=0;i<11;i++){ float tt=(float)i-5.0f; g[i]=expf(-(tt*tt)/4.5f); s+=g[i]; } for(int i=0;i<11;i++) g[i]/=s; }
  for (int i = tid; i < 74*3; i += 256){
    int j = i/3, widx = i - j*3;
    int gy = refl(y0 - 5 + j, HH);
    int gw = tx - 1 + widx;
    wds[j][widx] = (gw >= 0 && gw < 8) ? S[img*4096 + gy*8 + gw] : 0ull;
  }
  __syncthreads();
  for (int i = tid; i < 74*64; i += 256){
    int j = i >> 6, c = i & 63;
    float acc = 0.0f;
    for (int k = 0; k < 11; k++){
      int xx = refl(x0 + c + k - 5, WW);
      int widx = (xx >> 6) - tx + 1;
      float bv = (float)((wds[j][widx] >> (xx & 63)) & 1ull);
      acc += g[k] * bv;
    }
    hb[j][c] = acc;
  }
  __syncthreads();
  float mn = 3.4e38f, mx = -3.4e38f;
  float* ob = out + (size_t)img*HW;
  for (int i = tid; i < 4096; i += 256){
    int y = i >> 6, c = i & 63;
    float acc = 0.0f;
    for (int k = 0; k < 11; k++) acc += g[k] * hb[y + k][c];
    ob[(y0 + y)*WW + x0 + c] = acc;
    mn = fminf(mn, acc); mx = fmaxf(mx, acc);
  }
  for (int off = 32; off >= 1; off >>= 1){
    mn = fminf(mn, __shfl_down(mn, off));
    mx = fmaxf(mx, __shfl_down(mx, off));
  }
  int wv = tid >> 6, ln = tid & 63;
  if (ln == 0){ smn[wv] = mn; smx[wv] = mx; }
  __syncthreads();
  if (tid == 0){
    part[b] = make_float2(fminf(fminf(smn[0],smn[1]),fminf(smn[2],smn[3])),
                          fmaxf(fmaxf(smx[0],smx[1]),fmaxf(smx[2],smx[3])));
  }
}

// ---------------- edge min/max partials + sparsity min/max ----------------
__global__ void __launch_bounds__(256) k_edred(const float2* __restrict__ part,
                                               const uint32_t* __restrict__ hist,
                                               uint32_t* __restrict__ stats){
  __shared__ uint32_t sx[4], sn[4];
  int img = blockIdx.x;
  int tid = threadIdx.x;
  uint32_t mx = 0u, mn = 0xFFFFFFFFu;
  for (int i = tid; i < NBINS; i += 256){
    uint32_t c = hist[img*NBINS + i];
    if (c > mx) mx = c;
    if (c > 0u && c < mn) mn = c;
  }
  for (int off = 32; off >= 1; off >>= 1){
    uint32_t ox = (uint32_t)__shfl_down((int)mx, off);
    uint32_t on = (uint32_t)__shfl_down((int)mn, off);
    if (ox > mx) mx = ox;
    if (on < mn) mn = on;
  }
  int wv = tid >> 6, ln = tid & 63;
  if (ln == 0){ sx[wv] = mx; sn[wv] = mn; }
  float fmn = 3.4e38f, fmx = -3.4e38f;
  if (wv == 0){
    float2 v = part[img*64 + ln];
    fmn = v.x; fmx = v.y;
    for (int off = 32; off >= 1; off >>= 1){
      fmn = fminf(fmn, __shfl_down(fmn, off));
      fmx = fmaxf(fmx, __shfl_down(fmx, off));
    }
  }
  __syncthreads();
  if (tid == 0){
    uint32_t MX = max(max(sx[0],sx[1]), max(sx[2],sx[3]));
    uint32_t MN = min(min(sn[0],sn[1]), min(sn[2],sn[3]));
    stats[img*4+0] = __float_as_uint(fmn);
    stats[img*4+1] = __float_as_uint(fmx);
    stats[img*4+2] = __float_as_uint(-logf((float)MX / 262144.0f + 1e-9f));
    stats[img*4+3] = __float_as_uint(-logf((float)MN / 262144.0f + 1e-9f));
  }
}

// ---------------- fuse: normalize both maps, sigmoid (4 px/thread) ----------------
__global__ void __launch_bounds__(256) k_final(const float* __restrict__ ed,
                        const uint16_t* __restrict__ comb,
                        const uint32_t* __restrict__ hist, const uint32_t* __restrict__ stats,
                        const float* __restrict__ alpha, const float* __restrict__ beta,
                        float* __restrict__ out)
{
#pragma clang fp contract(off)
  int idx = blockIdx.x * 256 + threadIdx.x;      // float4 units
  int img = idx >> 16;
  float a = alpha[0], b = beta[0];
  float mne = __uint_as_float(stats[img*4+0]);
  float mxe = __uint_as_float(stats[img*4+1]);
  float mns = __uint_as_float(stats[img*4+2]);
  float mxs = __uint_as_float(stats[img*4+3]);
  float4 e4 = *(const float4*)(ed + (size_t)idx*4);
  ushort4 c4 = *(const ushort4*)(comb + (size_t)idx*4);
  const uint32_t* gh = hist + img*NBINS;
  float ee[4] = {e4.x, e4.y, e4.z, e4.w};
  uint16_t cc[4] = {c4.x, c4.y, c4.z, c4.w};
  float oo[4];
  #pragma unroll
  for (int j = 0; j < 4; j++){
    float sp = -logf((float)gh[cc[j]] / 262144.0f + 1e-9f);
    float en = (ee[j] - mne) / (mxe - mne + 1e-9f);
    float sn = (sp - mns) / (mxs - mns + 1e-9f);
    float f  = a*en + b*sn;
    oo[j] = 1.0f / (1.0f + expf(-f));
  }
  *(float4*)(out + (size_t)idx*4) = make_float4(oo[0], oo[1], oo[2], oo[3]);
}

extern "C" void kernel_launch(void* const* d_in, const int* in_sizes, int n_in,
                              void* d_out, int out_size, void* d_ws, size_t ws_size,
                              hipStream_t stream)
{
  const float* x     = (const float*)d_in[0];
  const float* mean  = (const float*)d_in[1];
  const float* stdv  = (const float*)d_in[2];
  const float* alpha = (const float*)d_in[3];
  const float* beta  = (const float*)d_in[4];
  float* out = (float*)d_out;

  char* ws = (char*)d_ws;
  float*    gray  = (float*)ws;                             // 16 MB
  uint16_t* comb  = (uint16_t*)(ws + (16u << 20));          // 8 MB
  float2*   part  = (float2*)(ws + (24u << 20));            // 8 KB
  uint32_t* hist  = (uint32_t*)(ws + (25u << 20));          // 256 KB
  u64*      Ab    = (u64*)(ws + (26u << 20));               // 512 KB
  u64*      Sb    = (u64*)(ws + (27u << 20));               // 512 KB
  uint32_t* stats = (uint32_t*)(ws + (28u << 20));          // 256 B

  hipLaunchKernelGGL(k_gray,  dim3(1024),  dim3(256), 0, stream, x, mean, stdv, gray, comb, (uint4*)hist);
  hipLaunchKernelGGL(k_canny, dim3(2048),  dim3(256), 0, stream, gray, Ab, Sb);
  hipLaunchKernelGGL(k_mid,   dim3(528),   dim3(512), 0, stream, Ab, Sb, comb, hist);
  hipLaunchKernelGGL(k_b11,   dim3(1024),  dim3(256), 0, stream, Sb, out, part);
  hipLaunchKernelGGL(k_edred, dim3(NB),    dim3(256), 0, stream, part, hist, stats);
  hipLaunchKernelGGL(k_final, dim3(4096),  dim3(256), 0, stream, out, comb, hist, stats, alpha, beta, out);
}